// Round 8
// baseline (157.111 us; speedup 1.0000x reference)
//
#include <hip/hip_runtime.h>
#include <hip/hip_bf16.h>

typedef __hip_bfloat16 bf16;
typedef __hip_bfloat162 bf162;
typedef _Float16 f16;
typedef __attribute__((ext_vector_type(2))) _Float16 h2;
typedef __attribute__((ext_vector_type(4))) _Float16 f16x4;
typedef __attribute__((ext_vector_type(8))) short short8;
typedef __attribute__((ext_vector_type(4))) short short4v;
typedef __attribute__((ext_vector_type(4))) float f32x4;

#define B_ 4
#define R_ 512
#define C_ 512
#define E_ 256
#define H_ 16
#define D_ 16

__device__ __forceinline__ float b2f(bf16 x) { return __bfloat162float(x); }
__device__ __forceinline__ void stout(bf16* p, float v) { *p = __float2bfloat16(v); }
__device__ __forceinline__ void stout(f16* p, float v) { *p = (f16)v; }

// ================= MFMA GEMM body =================
// AMODE: 0 = bf16 A, 1 = fp32 A (cvt), 2 = instance-norm bf16 A (normS,g,b)
// RES: 0 none, 1 fp32 ptr, 3 instance-norm(bf16 Res); STATS: sum/sumsq atomics
// BSRC: 0 = pre-transposed bf16 BT [N][K]; 1 = fp32 W [K][N], inline transpose+cvt (*wscl)
template <int AMODE, typename OT, int BM, int BN, bool BIAS, int RES, bool RELU, bool STATS, int BSRC = 0>
__device__ __forceinline__ void mfma_gemm_body(
    const void* __restrict__ Ap, const bf16* __restrict__ BT,
    const float* __restrict__ bias, const void* __restrict__ Res,
    const float* __restrict__ normS, const float* __restrict__ normG, const float* __restrict__ normB,
    float* __restrict__ statsOut, OT* __restrict__ Cout,
    int M, int N, int K, int bx, int by, float wscl = 1.0f)
{
    constexpr int MT = BM / 32, NT = BN / 32;
    constexpr int AEL = BM * 64 / 256, BEL = BN * 64 / 256;
    __shared__ __align__(16) bf16 As[BM * 80];
    __shared__ __align__(16) bf16 Bs[BN * 80];
    const int tid = threadIdx.x;
    const int wid = tid >> 6, lane = tid & 63;
    const int wm = wid >> 1, wn = wid & 1;
    const int fr = lane & 15, quad = lane >> 4;
    const int m0 = by * BM, n0 = bx * BN;
    const int arow = (AEL == 16) ? (tid >> 2) : (tid >> 3);
    const int akg  = (AEL == 16) ? ((tid & 3) << 4) : ((tid & 7) << 3);
    const int brow = (BEL == 16) ? (tid >> 2) : (tid >> 3);
    const int bkg  = (BEL == 16) ? ((tid & 3) << 4) : ((tid & 7) << 3);

    f32x4 acc[MT][NT];
#pragma unroll
    for (int mt = 0; mt < MT; mt++)
#pragma unroll
        for (int nt = 0; nt < NT; nt++) acc[mt][nt] = (f32x4){0.f, 0.f, 0.f, 0.f};

    for (int k0 = 0; k0 < K; k0 += 64) {
        // ---- stage A ----
        if constexpr (AMODE == 0) {
            const short8* gp = (const short8*)((const bf16*)Ap + (size_t)(m0 + arow) * K + k0 + akg);
#pragma unroll
            for (int t8 = 0; t8 < AEL / 8; t8++) *(short8*)(&As[arow * 80 + akg + 8 * t8]) = gp[t8];
        } else if constexpr (AMODE == 1) {
            const float4* gp = (const float4*)((const float*)Ap + (size_t)(m0 + arow) * K + k0 + akg);
#pragma unroll
            for (int j = 0; j < AEL / 4; j++) {
                const float4 f = gp[j];
                *(bf162*)(&As[arow * 80 + akg + j * 4])     = __float22bfloat162_rn(make_float2(f.x, f.y));
                *(bf162*)(&As[arow * 80 + akg + j * 4 + 2]) = __float22bfloat162_rn(make_float2(f.z, f.w));
            }
        } else {  // AMODE == 2: instance-norm A
            const int bb = (m0 + arow) >> 9;
            const bf16* ap = (const bf16*)Ap + (size_t)(m0 + arow) * K + k0 + akg;
            bf16 tmp[AEL];
#pragma unroll
            for (int t8 = 0; t8 < AEL / 8; t8++) *(short8*)(tmp + 8 * t8) = ((const short8*)ap)[t8];
#pragma unroll
            for (int j = 0; j < AEL; j++) {
                const int e = k0 + akg + j;
                const float s = normS[bb * 256 + e], sq = normS[1024 + bb * 256 + e];
                const float mn = s * (1.f / 512.f);
                float var = sq * (1.f / 512.f) - mn * mn; var = fmaxf(var, 0.f);
                As[arow * 80 + akg + j] = __float2bfloat16(
                    (b2f(tmp[j]) - mn) * rsqrtf(var + 1e-5f) * normG[e] + normB[e]);
            }
        }
        // ---- stage B ----
        if constexpr (BSRC == 0) {
            const short8* gp = (const short8*)(BT + (size_t)(n0 + brow) * K + k0 + bkg);
#pragma unroll
            for (int t8 = 0; t8 < BEL / 8; t8++) *(short8*)(&Bs[brow * 80 + bkg + 8 * t8]) = gp[t8];
        } else {
            // inline transpose from fp32 W[K][N]: thread group covers 64 k-rows x BN/4 n-cols
            constexpr int NSEG = BN / 4;
            const int kk = tid & 63;
            const int ns = (tid >> 6) * NSEG;
            const float* wp = (const float*)BT + (size_t)(k0 + kk) * N + n0 + ns;
#pragma unroll
            for (int j4 = 0; j4 < NSEG / 4; j4++) {
                const float4 f = *(const float4*)(wp + 4 * j4);
                Bs[(ns + 4 * j4 + 0) * 80 + kk] = __float2bfloat16(wscl * f.x);
                Bs[(ns + 4 * j4 + 1) * 80 + kk] = __float2bfloat16(wscl * f.y);
                Bs[(ns + 4 * j4 + 2) * 80 + kk] = __float2bfloat16(wscl * f.z);
                Bs[(ns + 4 * j4 + 3) * 80 + kk] = __float2bfloat16(wscl * f.w);
            }
        }
        __syncthreads();

        short8 af[MT][2], bfr[NT][2];
#pragma unroll
        for (int mt = 0; mt < MT; mt++) {
            const int ar = wm * (BM / 2) + mt * 16 + fr;
#pragma unroll
            for (int kh = 0; kh < 2; kh++)
                af[mt][kh] = *(const short8*)(&As[ar * 80 + quad * 8 + kh * 32]);
        }
#pragma unroll
        for (int nt = 0; nt < NT; nt++) {
            const int br = wn * (BN / 2) + nt * 16 + fr;
#pragma unroll
            for (int kh = 0; kh < 2; kh++)
                bfr[nt][kh] = *(const short8*)(&Bs[br * 80 + quad * 8 + kh * 32]);
        }
#pragma unroll
        for (int kh = 0; kh < 2; kh++)
#pragma unroll
            for (int mt = 0; mt < MT; mt++)
#pragma unroll
                for (int nt = 0; nt < NT; nt++)
                    acc[mt][nt] = __builtin_amdgcn_mfma_f32_16x16x32_bf16(
                        af[mt][kh], bfr[nt][kh], acc[mt][nt], 0, 0, 0);
        __syncthreads();
    }

    // ---- epilogue (C/D: col=lane&15, row=quad*4+reg) ----
    float vsum[NT], vss[NT];
#pragma unroll
    for (int nt = 0; nt < NT; nt++) { vsum[nt] = 0.f; vss[nt] = 0.f; }
#pragma unroll
    for (int mt = 0; mt < MT; mt++) {
#pragma unroll
        for (int nt = 0; nt < NT; nt++) {
#pragma unroll
            for (int i = 0; i < 4; i++) {
                const int row = m0 + wm * (BM / 2) + mt * 16 + quad * 4 + i;
                const int col = n0 + wn * (BN / 2) + nt * 16 + fr;
                float v = acc[mt][nt][i];
                if (BIAS) v += bias[col];
                if constexpr (RES == 1) v += ((const float*)Res)[(size_t)row * N + col];
                if constexpr (RES == 3) {
                    const int bb = row >> 9;
                    const float yv = b2f(((const bf16*)Res)[(size_t)row * N + col]);
                    const float s = normS[bb * 256 + col], sq = normS[1024 + bb * 256 + col];
                    const float mn = s * (1.f / 512.f);
                    float var = sq * (1.f / 512.f) - mn * mn; var = fmaxf(var, 0.f);
                    v += (yv - mn) * rsqrtf(var + 1e-5f) * normG[col] + normB[col];
                }
                if (RELU) v = fmaxf(v, 0.f);
                stout(&Cout[(size_t)row * N + col], v);
                if (STATS) { vsum[nt] += v; vss[nt] += v * v; }
            }
        }
    }
    if constexpr (STATS) {
        float* sred = (float*)As;  // alias dead A-tile
#pragma unroll
        for (int nt = 0; nt < NT; nt++) {
            float a = vsum[nt]; a += __shfl_xor(a, 16, 64); a += __shfl_xor(a, 32, 64);
            float c = vss[nt];  c += __shfl_xor(c, 16, 64); c += __shfl_xor(c, 32, 64);
            if (quad == 0) {
                const int cl = wn * (BN / 2) + nt * 16 + fr;
                sred[wm * (2 * BN) + cl * 2 + 0] = a;
                sred[wm * (2 * BN) + cl * 2 + 1] = c;
            }
        }
        __syncthreads();
        if (tid < 2 * BN) {
            const int cl = tid >> 1, w = tid & 1;
            const float tot = sred[cl * 2 + w] + sred[2 * BN + cl * 2 + w];
            atomicAdd(&statsOut[w * 1024 + (m0 >> 9) * 256 + n0 + cl], tot);
        }
    }
}

template <int AMODE, typename OT, int BM, int BN, bool BIAS, int RES, bool RELU, bool STATS>
__global__ __launch_bounds__(256) void mfma_gemm_kernel(
    const void* __restrict__ Ap, const bf16* __restrict__ BT,
    const float* __restrict__ bias, const void* __restrict__ Res,
    const float* __restrict__ normS, const float* __restrict__ normG, const float* __restrict__ normB,
    float* __restrict__ statsOut, OT* __restrict__ Cout, int M, int N, int K)
{
    mfma_gemm_body<AMODE, OT, BM, BN, BIAS, RES, RELU, STATS>(
        Ap, BT, bias, Res, normS, normG, normB, statsOut, Cout,
        M, N, K, blockIdx.x, blockIdx.y);
}

// ================= K12: fused prep + QKV (976 WGs) =================
// Blocks 0..383:   QKV GEMMs (32x128 tiles) reading fp32 Wq/Wk/Wv directly,
//                  transpose+cvt inline during B-staging (q scaled 0.25).
// Blocks 384..703: transpose/cvt Wc/W1/W2 -> bf16 [N][K] (needed by K4/K5/K6).
// Blocks 704..719: zero stats1+stats2 (4096 floats).
// Blocks 720..975: convert cost fp32 -> f16 (1,048,576 elems = 256 blk x 4096).
__global__ __launch_bounds__(256) void prep_qkv_kernel(
    const float* __restrict__ rowE, const float* __restrict__ colE,
    const float* __restrict__ Wq, const float* __restrict__ Wk, const float* __restrict__ Wv,
    const float* __restrict__ Wc, const float* __restrict__ W1, const float* __restrict__ W2,
    const float* __restrict__ cost,
    bf16* __restrict__ WcT, bf16* __restrict__ W1T, bf16* __restrict__ W2T,
    float* __restrict__ statsZ, f16* __restrict__ costh,
    f16* __restrict__ qo, f16* __restrict__ ko, f16* __restrict__ vo)
{
    const int bid = blockIdx.x;
    const int tid = threadIdx.x;

    if (bid >= 720) {  // cost fp32 -> f16, 4096 elems/block, 256 blocks = 1M elems total
        const int base = (bid - 720) * 4096 + tid * 16;
        const float4* cp = (const float4*)(cost + base);
        f16 tmp[16];
#pragma unroll
        for (int j = 0; j < 4; j++) {
            const float4 f = cp[j];
            tmp[4 * j + 0] = (f16)f.x; tmp[4 * j + 1] = (f16)f.y;
            tmp[4 * j + 2] = (f16)f.z; tmp[4 * j + 3] = (f16)f.w;
        }
        *(short8*)(costh + base)     = *(short8*)(tmp);
        *(short8*)(costh + base + 8) = *(short8*)(tmp + 8);
        return;
    }
    if (bid >= 384) {
        const int spare = bid - 384;
        if (spare >= 320) {  // zero stats1+stats2
            statsZ[(spare - 320) * 256 + tid] = 0.f;
            return;
        }
        // weight transpose/cvt fp32 [K][N] -> bf16 [N][K]
        __shared__ bf16 tile[32][33];
        const float* src; bf16* dst; int K, N, tix;
        if (spare < 64)       { src = Wc; dst = WcT; K = 256; N = 256; tix = spare; }
        else if (spare < 192) { src = W1; dst = W1T; K = 256; N = 512; tix = spare - 64; }
        else                  { src = W2; dst = W2T; K = 512; N = 256; tix = spare - 192; }
        const int ncnt = N >> 5;
        const int tk = tix / ncnt, tn = tix % ncnt;
        const int c = tid & 31, r = tid >> 5;
#pragma unroll
        for (int i = 0; i < 4; i++)
            tile[r + i * 8][c] = __float2bfloat16(src[(size_t)(tk * 32 + r + i * 8) * N + tn * 32 + c]);
        __syncthreads();
#pragma unroll
        for (int i = 0; i < 4; i++)
            dst[(size_t)(tn * 32 + r + i * 8) * K + tk * 32 + c] = tile[c][r + i * 8];
        return;
    }

    // ---- QKV GEMM: 32x128 tile, B transposed inline from fp32 [256][256] ----
    const int z = bid >> 7;            // 0=q 1=k 2=v (128 blocks each)
    const int rem = bid & 127;
    const int bx = rem & 1, by = rem >> 1;
    const float* A = (z == 0) ? rowE : colE;
    const float* W = (z == 0) ? Wq : (z == 1) ? Wk : Wv;
    f16* out = (z == 0) ? qo : (z == 1) ? ko : vo;
    const float scl = (z == 0) ? 0.25f : 1.0f;

    mfma_gemm_body<1, f16, 32, 128, false, 0, false, false, 1>(
        A, (const bf16*)W, nullptr, nullptr, nullptr, nullptr, nullptr, nullptr, out,
        2048, 256, 256, bx, by, scl);
}

// ================= K3: attention, fully fused over all 512 cols =================
// Grid (rt8, h16, b4) = 512 WGs x 4 waves; wave owns rows [rt*64+wid*16, +16).
// S^T = K . q via mfma_16x16x16_f16; C-frag (c_local=quad*4+i, r=fr) -> lane holds
// 32 scores of its own row fr; exp'd scores ARE the PV B-frag (i==j).
// O^T = V^T . P^T (A = V^T from LDS [d][c], stride 520). Online softmax over 4 chunks.
// Cost read as pre-converted f16 (halves traffic + cf registers).
__global__ __launch_bounds__(256) void attn_kernel(
    const f16* __restrict__ q, const f16* __restrict__ k, const f16* __restrict__ v,
    const f16* __restrict__ costh, const float* __restrict__ m1w, const float* __restrict__ m1b,
    const float* __restrict__ m2w, const float* __restrict__ m2b,
    bf16* __restrict__ sa)
{
    __shared__ __align__(16) short kbuf[512 * 16];       // 16 KB, [c][d ^ ((c&1)<<3)]
    __shared__ __align__(16) _Float16 vbufT[16 * 520];   // 16.25 KB, [d][c], stride 520

    const int rt = blockIdx.x, h = blockIdx.y, b = blockIdx.z;
    const int tid = threadIdx.x, wid = tid >> 6, lane = tid & 63;
    const int quad = lane >> 4, fr = lane & 15;
    const int row_m = rt * 64 + wid * 16 + fr;

    // ---- this lane's q fragment: B[k=quad*4+j][n=fr] = q[row fr][d=quad*4+j] ----
    const f16x4 qf = *(const f16x4*)(q + (size_t)(b * R_ + row_m) * 256 + h * 16 + (quad << 2));

    // ---- stage K [c][d] (xor-swizzled) and V^T [d][c] for all 512 cols ----
    {
        const int lc0 = tid >> 1, dp = (tid & 1) * 8;
        const size_t gbase = (size_t)(b * C_) * 256 + h * 16 + dp;
#pragma unroll
        for (int it = 0; it < 4; it++) {
            const int lc = it * 128 + lc0;
            const size_t g = gbase + (size_t)lc * 256;
            *(short8*)(&kbuf[lc * 16 + (dp ^ ((lc & 1) << 3))]) = *(const short8*)(k + g);
            const short8 vv = *(const short8*)(v + g);
#pragma unroll
            for (int u = 0; u < 8; u++) vbufT[(dp + u) * 520 + lc] = ((const _Float16*)&vv)[u];
        }
    }

    // ---- per-head MLP weights (packed f16 pairs over hidden dim m) ----
    h2 w1a2[8], w1b2[8], b1h[8], w2p[8];
#pragma unroll
    for (int i = 0; i < 8; i++) {
        h2 t;
        t.x = (f16)m1w[h * 32 + 2 * i];      t.y = (f16)m1w[h * 32 + 2 * i + 1];      w1a2[i] = t;
        t.x = (f16)m1w[h * 32 + 16 + 2 * i]; t.y = (f16)m1w[h * 32 + 17 + 2 * i];     w1b2[i] = t;
        t.x = (f16)m1b[h * 16 + 2 * i];      t.y = (f16)m1b[h * 16 + 2 * i + 1];      b1h[i] = t;
        t.x = (f16)m2w[h * 16 + 2 * i];      t.y = (f16)m2w[h * 16 + 2 * i + 1];      w2p[i] = t;
    }
    const float b2v = m2b[h];
    const h2 zero2 = (h2)(f16)0;

    // ---- cost prefetch (chunk 0), f16x4 per t ----
    const f16* crow = costh + (size_t)(b * R_ + row_m) * C_;
    f16x4 cf[2][8];
#pragma unroll
    for (int t = 0; t < 8; t++) cf[0][t] = *(const f16x4*)(crow + t * 16 + (quad << 2));

    __syncthreads();

    f32x4 oaccT = (f32x4){0.f, 0.f, 0.f, 0.f};
    float lsum = 0.f, m_run = -3.0e30f;

#pragma unroll
    for (int cs = 0; cs < 4; cs++) {
        // prefetch next chunk's cost (covered by this chunk's compute)
        if (cs < 3) {
#pragma unroll
            for (int t = 0; t < 8; t++)
                cf[(cs + 1) & 1][t] = *(const f16x4*)(crow + (cs + 1) * 128 + t * 16 + (quad << 2));
        }
        // ---- S^T via MFMA: sc[t][i] = dot(q[fr], k[c]) at c = cs*128 + t*16 + quad*4 + i ----
        f32x4 sc[8];
#pragma unroll
        for (int t = 0; t < 8; t++) {
            const int c = cs * 128 + t * 16 + fr;
            const f16x4 kf = *(const f16x4*)(&kbuf[c * 16 + ((quad << 2) ^ ((fr & 1) << 3))]);
            sc[t] = __builtin_amdgcn_mfma_f32_16x16x16f16(kf, qf, (f32x4){0.f, 0.f, 0.f, 0.f}, 0, 0, 0);
        }
        // ---- per-score 2->16->1 mixing MLP (h2 over hidden dim) ----
#pragma unroll
        for (int t = 0; t < 8; t++) {
            const f16x4 cq = cf[cs & 1][t];
#pragma unroll
            for (int i = 0; i < 4; i++) {
                const f16 doth = (f16)sc[t][i], csth = cq[i];
                h2 dot2; dot2.x = doth; dot2.y = doth;
                h2 cst2; cst2.x = csth; cst2.y = csth;
                h2 acc2 = zero2;
#pragma unroll
                for (int mm = 0; mm < 8; mm++) {
                    h2 tt = dot2 * w1a2[mm] + b1h[mm];
                    tt = cst2 * w1b2[mm] + tt;
                    tt = __builtin_elementwise_max(tt, zero2);
                    acc2 = tt * w2p[mm] + acc2;
                }
                sc[t][i] = b2v + (float)acc2.x + (float)acc2.y;
            }
        }
        // ---- online softmax update (row = fr; lane-local + 2 shuffles) ----
        float mx = fmaxf(fmaxf(sc[0][0], sc[0][1]), fmaxf(sc[0][2], sc[0][3]));
#pragma unroll
        for (int t = 1; t < 8; t++)
            mx = fmaxf(mx, fmaxf(fmaxf(sc[t][0], sc[t][1]), fmaxf(sc[t][2], sc[t][3])));
        mx = fmaxf(mx, __shfl_xor(mx, 16, 64));
        mx = fmaxf(mx, __shfl_xor(mx, 32, 64));
        const float mnew = fmaxf(m_run, mx);
        const float fac = __expf(m_run - mnew);
        m_run = mnew;
        lsum *= fac;
        oaccT[0] *= fac; oaccT[1] *= fac; oaccT[2] *= fac; oaccT[3] *= fac;

        // ---- exp + PV MFMA: B-frag = exp'd scores in-register (i == j) ----
#pragma unroll
        for (int p = 0; p < 8; p++) {
            f16x4 pf;
#pragma unroll
            for (int j = 0; j < 4; j++) {
                const float e = __expf(sc[p][j] - m_run);
                lsum += e;
                pf[j] = (f16)e;
            }
            const f16x4 vf = *(const f16x4*)(&vbufT[fr * 520 + cs * 128 + p * 16 + (quad << 2)]);
            oaccT = __builtin_amdgcn_mfma_f32_16x16x16f16(vf, pf, oaccT, 0, 0, 0);
        }
    }

    // ---- normalize and write: lane holds O[row fr][d = quad*4 + i] ----
    lsum += __shfl_xor(lsum, 16, 64);
    lsum += __shfl_xor(lsum, 32, 64);
    const float inv = 1.f / lsum;
    short4v o;
#pragma unroll
    for (int i = 0; i < 4; i++) o[i] = __builtin_bit_cast(short, __float2bfloat16(oaccT[i] * inv));
    *(short4v*)((short*)sa + (size_t)(b * R_ + row_m) * 256 + h * 16 + (quad << 2)) = o;
}

// ================= K7: final instance-norm from raw stats -> fp32 out =================
__global__ __launch_bounds__(256) void apply_in2_kernel(
    const bf16* __restrict__ xin, const float* __restrict__ stats,
    const float* __restrict__ g, const float* __restrict__ be, float* __restrict__ outp)
{
    const int base = (blockIdx.x * 256 + threadIdx.x) * 4;  // < 524288
    const int b = base >> 17;
    const bf162* xp = (const bf162*)(xin + base);
    const float2 x0 = __bfloat1622float2(xp[0]), x1 = __bfloat1622float2(xp[1]);
    const float xv[4] = {x0.x, x0.y, x1.x, x1.y};
    float4 rr;
    float* rp = (float*)&rr;
#pragma unroll
    for (int j = 0; j < 4; j++) {
        const int e = (base & 255) + j;
        const float s = stats[b * 256 + e], sq = stats[1024 + b * 256 + e];
        const float mn = s * (1.f / 512.f);
        float var = sq * (1.f / 512.f) - mn * mn; var = fmaxf(var, 0.f);
        rp[j] = (xv[j] - mn) * rsqrtf(var + 1e-5f) * g[e] + be[e];
    }
    *(float4*)(outp + base) = rr;
}

extern "C" void kernel_launch(void* const* d_in, const int* in_sizes, int n_in,
                              void* d_out, int out_size, void* d_ws, size_t ws_size,
                              hipStream_t stream)
{
    (void)in_sizes; (void)n_in; (void)out_size; (void)ws_size;
    const float* row_emb = (const float*)d_in[0];
    const float* col_emb = (const float*)d_in[1];
    const float* cost    = (const float*)d_in[2];
    const float* Wq  = (const float*)d_in[3];
    const float* Wk  = (const float*)d_in[4];
    const float* Wv  = (const float*)d_in[5];
    const float* m1w = (const float*)d_in[6];
    const float* m1b = (const float*)d_in[7];
    const float* m2w = (const float*)d_in[8];
    const float* m2b = (const float*)d_in[9];
    const float* Wc  = (const float*)d_in[10];
    const float* bc  = (const float*)d_in[11];
    const float* W1  = (const float*)d_in[12];
    const float* b1  = (const float*)d_in[13];
    const float* W2  = (const float*)d_in[14];
    const float* b2  = (const float*)d_in[15];
    const float* g1  = (const float*)d_in[16];
    const float* be1 = (const float*)d_in[17];
    const float* g2  = (const float*)d_in[18];
    const float* be2 = (const float*)d_in[19];
    float* out = (float*)d_out;

    // ---- workspace layout (~12 MB used) ----
    char* w = (char*)d_ws;
    const size_t MB = 1u << 20;
    f16*  sq  = (f16*)(w + 0 * MB);        // 1 MB [K12..K3]
    f16*  sk  = (f16*)(w + 1 * MB);        // 1 MB [K12..K3]
    f16*  sv  = (f16*)(w + 2 * MB);        // 1 MB [K12..K3]
    bf16* sa  = (bf16*)(w + 3 * MB);       // 1 MB [K3..K4]
    bf16* sy  = (bf16*)(w + 4 * MB);       // 1 MB [K4..K6]
    bf16* st  = (bf16*)(w + 5 * MB);       // 1 MB [K6..K7]
    bf16* shm = (bf16*)(w + 6 * MB);       // 2 MB [K5..K6]
    bf16* WcT = (bf16*)(w + 8 * MB);       // 128 KB
    bf16* W1T = WcT + 65536;               // 256 KB
    bf16* W2T = W1T + 131072;              // 256 KB
    float* stats1 = (float*)(w + 9 * MB);  // 8 KB
    float* stats2 = stats1 + 2048;         // 8 KB
    f16*  costh = (f16*)(w + 10 * MB);     // 2 MB (1M f16) [K12..K3]

    const dim3 blk(256);

    // K12: fused prep (Wc/W1/W2 transpose + stats zero + cost->f16) || QKV (32x128) inline W transpose
    prep_qkv_kernel<<<dim3(976), blk, 0, stream>>>(
        row_emb, col_emb, Wq, Wk, Wv, Wc, W1, W2, cost,
        WcT, W1T, W2T, stats1, costh, sq, sk, sv);

    // K3: fully-fused attention (512 WGs, 33 KB LDS, MFMA QK^T + MFMA PV, online softmax)
    attn_kernel<<<dim3(8, 16, 4), blk, 0, stream>>>(
        sq, sk, sv, costh, m1w, m1b, m2w, m2b, sa);

    // K4: y = sa @ Wc + bc + row_emb -> sy (+stats1)  [512 WGs, 32x32]
    mfma_gemm_kernel<0, bf16, 32, 32, true, 1, false, true><<<dim3(8, 64), blk, 0, stream>>>(
        sa, WcT, bc, row_emb, nullptr, nullptr, nullptr, stats1, sy, 2048, 256, 256);

    // K5: hm = relu(norm1(sy) @ W1 + b1) -> shm  [512 WGs, 32x64]
    mfma_gemm_kernel<2, bf16, 32, 64, true, 0, true, false><<<dim3(8, 64), blk, 0, stream>>>(
        sy, W1T, b1, nullptr, stats1, g1, be1, nullptr, shm, 2048, 512, 256);

    // K6: t = hm @ W2 + b2 + norm1(sy) -> st (+stats2)  [512 WGs, 32x32]
    mfma_gemm_kernel<0, bf16, 32, 32, true, 3, false, true><<<dim3(8, 64), blk, 0, stream>>>(
        shm, W2T, b2, sy, stats1, g1, be1, stats2, st, 2048, 256, 512);

    // K7: out = norm2(st)
    apply_in2_kernel<<<dim3(512), blk, 0, stream>>>(st, stats2, g2, be2, out);
}

// Round 9
// 150.970 us; speedup vs baseline: 1.0407x; 1.0407x over previous
//
#include <hip/hip_runtime.h>
#include <hip/hip_bf16.h>

typedef __hip_bfloat16 bf16;
typedef __hip_bfloat162 bf162;
typedef _Float16 f16;
typedef __attribute__((ext_vector_type(2))) _Float16 h2;
typedef __attribute__((ext_vector_type(4))) _Float16 f16x4;
typedef __attribute__((ext_vector_type(8))) short short8;
typedef __attribute__((ext_vector_type(4))) short short4v;
typedef __attribute__((ext_vector_type(4))) float f32x4;

#define B_ 4
#define R_ 512
#define C_ 512
#define E_ 256
#define H_ 16
#define D_ 16

__device__ __forceinline__ float b2f(bf16 x) { return __bfloat162float(x); }
__device__ __forceinline__ void stout(bf16* p, float v) { *p = __float2bfloat16(v); }
__device__ __forceinline__ void stout(f16* p, float v) { *p = (f16)v; }

// ================= MFMA GEMM body =================
// AMODE: 0 = bf16 A, 1 = fp32 A (cvt), 2 = instance-norm bf16 A (normS,g,b; K must be 256)
// RES: 0 none, 1 fp32 ptr, 3 instance-norm(bf16 Res); STATS: sum/sumsq atomics
// BSRC: 0 = pre-transposed bf16 BT [N][K]; 1 = fp32 W [K][N], inline transpose+cvt (*wscl)
template <int AMODE, typename OT, int BM, int BN, bool BIAS, int RES, bool RELU, bool STATS, int BSRC = 0>
__device__ __forceinline__ void mfma_gemm_body(
    const void* __restrict__ Ap, const bf16* __restrict__ BT,
    const float* __restrict__ bias, const void* __restrict__ Res,
    const float* __restrict__ normS, const float* __restrict__ normG, const float* __restrict__ normB,
    float* __restrict__ statsOut, OT* __restrict__ Cout,
    int M, int N, int K, int bx, int by, float wscl = 1.0f)
{
    constexpr int MT = BM / 32, NT = BN / 32;
    constexpr int AEL = BM * 64 / 256, BEL = BN * 64 / 256;
    __shared__ __align__(16) bf16 As[BM * 80];
    __shared__ __align__(16) bf16 Bs[BN * 80];
    __shared__ float nsc[(AMODE == 2) ? 256 : 1];
    __shared__ float nsh[(AMODE == 2) ? 256 : 1];
    const int tid = threadIdx.x;
    const int wid = tid >> 6, lane = tid & 63;
    const int wm = wid >> 1, wn = wid & 1;
    const int fr = lane & 15, quad = lane >> 4;
    const int m0 = by * BM, n0 = bx * BN;
    const int arow = (AEL == 16) ? (tid >> 2) : (tid >> 3);
    const int akg  = (AEL == 16) ? ((tid & 3) << 4) : ((tid & 7) << 3);
    const int brow = (BEL == 16) ? (tid >> 2) : (tid >> 3);
    const int bkg  = (BEL == 16) ? ((tid & 3) << 4) : ((tid & 7) << 3);

    if constexpr (AMODE == 2) {
        // per-column norm scale/shift (K == 256; all rows of this block share batch bb)
        const int bb = m0 >> 9;
        const int e = tid;
        const float s = normS[bb * 256 + e], sq = normS[1024 + bb * 256 + e];
        const float mn = s * (1.f / 512.f);
        float var = sq * (1.f / 512.f) - mn * mn; var = fmaxf(var, 0.f);
        const float rs = rsqrtf(var + 1e-5f) * normG[e];
        nsc[e] = rs;
        nsh[e] = normB[e] - mn * rs;
        __syncthreads();
    }

    f32x4 acc[MT][NT];
#pragma unroll
    for (int mt = 0; mt < MT; mt++)
#pragma unroll
        for (int nt = 0; nt < NT; nt++) acc[mt][nt] = (f32x4){0.f, 0.f, 0.f, 0.f};

    for (int k0 = 0; k0 < K; k0 += 64) {
        // ---- stage A ----
        if constexpr (AMODE == 0) {
            const short8* gp = (const short8*)((const bf16*)Ap + (size_t)(m0 + arow) * K + k0 + akg);
#pragma unroll
            for (int t8 = 0; t8 < AEL / 8; t8++) *(short8*)(&As[arow * 80 + akg + 8 * t8]) = gp[t8];
        } else if constexpr (AMODE == 1) {
            const float4* gp = (const float4*)((const float*)Ap + (size_t)(m0 + arow) * K + k0 + akg);
#pragma unroll
            for (int j = 0; j < AEL / 4; j++) {
                const float4 f = gp[j];
                *(bf162*)(&As[arow * 80 + akg + j * 4])     = __float22bfloat162_rn(make_float2(f.x, f.y));
                *(bf162*)(&As[arow * 80 + akg + j * 4 + 2]) = __float22bfloat162_rn(make_float2(f.z, f.w));
            }
        } else {  // AMODE == 2: instance-norm A via precomputed scale/shift
            const bf16* ap = (const bf16*)Ap + (size_t)(m0 + arow) * K + k0 + akg;
            bf16 tmp[AEL];
#pragma unroll
            for (int t8 = 0; t8 < AEL / 8; t8++) *(short8*)(tmp + 8 * t8) = ((const short8*)ap)[t8];
#pragma unroll
            for (int j = 0; j < AEL; j++) {
                const int e = k0 + akg + j;
                As[arow * 80 + akg + j] = __float2bfloat16(b2f(tmp[j]) * nsc[e] + nsh[e]);
            }
        }
        // ---- stage B ----
        if constexpr (BSRC == 0) {
            const short8* gp = (const short8*)(BT + (size_t)(n0 + brow) * K + k0 + bkg);
#pragma unroll
            for (int t8 = 0; t8 < BEL / 8; t8++) *(short8*)(&Bs[brow * 80 + bkg + 8 * t8]) = gp[t8];
        } else {
            // inline transpose from fp32 W[K][N]: thread group covers 64 k-rows x BN/4 n-cols
            constexpr int NSEG = BN / 4;
            const int kk = tid & 63;
            const int ns = (tid >> 6) * NSEG;
            const float* wp = (const float*)BT + (size_t)(k0 + kk) * N + n0 + ns;
#pragma unroll
            for (int j4 = 0; j4 < NSEG / 4; j4++) {
                const float4 f = *(const float4*)(wp + 4 * j4);
                Bs[(ns + 4 * j4 + 0) * 80 + kk] = __float2bfloat16(wscl * f.x);
                Bs[(ns + 4 * j4 + 1) * 80 + kk] = __float2bfloat16(wscl * f.y);
                Bs[(ns + 4 * j4 + 2) * 80 + kk] = __float2bfloat16(wscl * f.z);
                Bs[(ns + 4 * j4 + 3) * 80 + kk] = __float2bfloat16(wscl * f.w);
            }
        }
        __syncthreads();

        short8 af[MT][2], bfr[NT][2];
#pragma unroll
        for (int mt = 0; mt < MT; mt++) {
            const int ar = wm * (BM / 2) + mt * 16 + fr;
#pragma unroll
            for (int kh = 0; kh < 2; kh++)
                af[mt][kh] = *(const short8*)(&As[ar * 80 + quad * 8 + kh * 32]);
        }
#pragma unroll
        for (int nt = 0; nt < NT; nt++) {
            const int br = wn * (BN / 2) + nt * 16 + fr;
#pragma unroll
            for (int kh = 0; kh < 2; kh++)
                bfr[nt][kh] = *(const short8*)(&Bs[br * 80 + quad * 8 + kh * 32]);
        }
#pragma unroll
        for (int kh = 0; kh < 2; kh++)
#pragma unroll
            for (int mt = 0; mt < MT; mt++)
#pragma unroll
                for (int nt = 0; nt < NT; nt++)
                    acc[mt][nt] = __builtin_amdgcn_mfma_f32_16x16x32_bf16(
                        af[mt][kh], bfr[nt][kh], acc[mt][nt], 0, 0, 0);
        __syncthreads();
    }

    // ---- epilogue (C/D: col=lane&15, row=quad*4+reg) ----
    float vsum[NT], vss[NT];
#pragma unroll
    for (int nt = 0; nt < NT; nt++) { vsum[nt] = 0.f; vss[nt] = 0.f; }
#pragma unroll
    for (int mt = 0; mt < MT; mt++) {
#pragma unroll
        for (int nt = 0; nt < NT; nt++) {
#pragma unroll
            for (int i = 0; i < 4; i++) {
                const int row = m0 + wm * (BM / 2) + mt * 16 + quad * 4 + i;
                const int col = n0 + wn * (BN / 2) + nt * 16 + fr;
                float v = acc[mt][nt][i];
                if (BIAS) v += bias[col];
                if constexpr (RES == 1) v += ((const float*)Res)[(size_t)row * N + col];
                if constexpr (RES == 3) {
                    const int bb = row >> 9;
                    const float yv = b2f(((const bf16*)Res)[(size_t)row * N + col]);
                    const float s = normS[bb * 256 + col], sq = normS[1024 + bb * 256 + col];
                    const float mn = s * (1.f / 512.f);
                    float var = sq * (1.f / 512.f) - mn * mn; var = fmaxf(var, 0.f);
                    v += (yv - mn) * rsqrtf(var + 1e-5f) * normG[col] + normB[col];
                }
                if (RELU) v = fmaxf(v, 0.f);
                stout(&Cout[(size_t)row * N + col], v);
                if (STATS) { vsum[nt] += v; vss[nt] += v * v; }
            }
        }
    }
    if constexpr (STATS) {
        float* sred = (float*)As;  // alias dead A-tile
#pragma unroll
        for (int nt = 0; nt < NT; nt++) {
            float a = vsum[nt]; a += __shfl_xor(a, 16, 64); a += __shfl_xor(a, 32, 64);
            float c = vss[nt];  c += __shfl_xor(c, 16, 64); c += __shfl_xor(c, 32, 64);
            if (quad == 0) {
                const int cl = wn * (BN / 2) + nt * 16 + fr;
                sred[wm * (2 * BN) + cl * 2 + 0] = a;
                sred[wm * (2 * BN) + cl * 2 + 1] = c;
            }
        }
        __syncthreads();
        if (tid < 2 * BN) {
            const int cl = tid >> 1, w = tid & 1;
            const float tot = sred[cl * 2 + w] + sred[2 * BN + cl * 2 + w];
            atomicAdd(&statsOut[w * 1024 + (m0 >> 9) * 256 + n0 + cl], tot);
        }
    }
}

template <int AMODE, typename OT, int BM, int BN, bool BIAS, int RES, bool RELU, bool STATS>
__global__ __launch_bounds__(256) void mfma_gemm_kernel(
    const void* __restrict__ Ap, const bf16* __restrict__ BT,
    const float* __restrict__ bias, const void* __restrict__ Res,
    const float* __restrict__ normS, const float* __restrict__ normG, const float* __restrict__ normB,
    float* __restrict__ statsOut, OT* __restrict__ Cout, int M, int N, int K)
{
    mfma_gemm_body<AMODE, OT, BM, BN, BIAS, RES, RELU, STATS>(
        Ap, BT, bias, Res, normS, normG, normB, statsOut, Cout,
        M, N, K, blockIdx.x, blockIdx.y);
}

// ================= K12: fused prep + QKV (1104 WGs) =================
// Blocks 0..767:     QKV GEMMs (32x64 tiles) reading fp32 Wq/Wk/Wv directly,
//                    transpose+cvt inline during B-staging (q scaled 0.25).
// Blocks 768..1087:  transpose/cvt Wc/W1/W2 -> bf16 [N][K] (needed by K4/K5/K6).
// Blocks 1088..1103: zero stats1+stats2 (4096 floats).
__global__ __launch_bounds__(256) void prep_qkv_kernel(
    const float* __restrict__ rowE, const float* __restrict__ colE,
    const float* __restrict__ Wq, const float* __restrict__ Wk, const float* __restrict__ Wv,
    const float* __restrict__ Wc, const float* __restrict__ W1, const float* __restrict__ W2,
    bf16* __restrict__ WcT, bf16* __restrict__ W1T, bf16* __restrict__ W2T,
    float* __restrict__ statsZ,
    f16* __restrict__ qo, f16* __restrict__ ko, f16* __restrict__ vo)
{
    const int bid = blockIdx.x;
    const int tid = threadIdx.x;

    if (bid >= 768) {
        const int spare = bid - 768;
        if (spare >= 320) {  // zero stats1+stats2
            statsZ[(spare - 320) * 256 + tid] = 0.f;
            return;
        }
        // weight transpose/cvt fp32 [K][N] -> bf16 [N][K]
        __shared__ bf16 tile[32][33];
        const float* src; bf16* dst; int K, N, tix;
        if (spare < 64)       { src = Wc; dst = WcT; K = 256; N = 256; tix = spare; }
        else if (spare < 192) { src = W1; dst = W1T; K = 256; N = 512; tix = spare - 64; }
        else                  { src = W2; dst = W2T; K = 512; N = 256; tix = spare - 192; }
        const int ncnt = N >> 5;
        const int tk = tix / ncnt, tn = tix % ncnt;
        const int c = tid & 31, r = tid >> 5;
#pragma unroll
        for (int i = 0; i < 4; i++)
            tile[r + i * 8][c] = __float2bfloat16(src[(size_t)(tk * 32 + r + i * 8) * N + tn * 32 + c]);
        __syncthreads();
#pragma unroll
        for (int i = 0; i < 4; i++)
            dst[(size_t)(tn * 32 + r + i * 8) * K + tk * 32 + c] = tile[c][r + i * 8];
        return;
    }

    // ---- QKV GEMM: 32x64 tile, B transposed inline from fp32 [256][256] ----
    const int z = bid >> 8;            // 0=q 1=k 2=v
    const int rem = bid & 255;
    const int bx = rem & 3, by = rem >> 2;
    const float* A = (z == 0) ? rowE : colE;
    const float* W = (z == 0) ? Wq : (z == 1) ? Wk : Wv;
    f16* out = (z == 0) ? qo : (z == 1) ? ko : vo;
    const float scl = (z == 0) ? 0.25f : 1.0f;

    mfma_gemm_body<1, f16, 32, 64, false, 0, false, false, 1>(
        A, (const bf16*)W, nullptr, nullptr, nullptr, nullptr, nullptr, nullptr, out,
        2048, 256, 256, bx, by, scl);
}

// ================= K3: attention, fully fused over all 512 cols =================
// Grid (rt8, h16, b4) = 512 WGs x 4 waves; wave owns rows [rt*64+wid*16, +16).
// S^T = K . q via mfma_16x16x16_f16; C-frag (c_local=quad*4+i, r=fr) -> lane holds
// 32 scores of its own row fr; exp'd scores ARE the PV B-frag (i==j).
// O^T = V^T . P^T (A = V^T from LDS [d][c], stride 524: separates d and d+8 write
// banks -> 2-way (free) instead of 4-way). Online softmax over 4 chunks.
__global__ __launch_bounds__(256) void attn_kernel(
    const f16* __restrict__ q, const f16* __restrict__ k, const f16* __restrict__ v,
    const float* __restrict__ cost, const float* __restrict__ m1w, const float* __restrict__ m1b,
    const float* __restrict__ m2w, const float* __restrict__ m2b,
    bf16* __restrict__ sa)
{
    __shared__ __align__(16) short kbuf[512 * 16];       // 16 KB, [c][d ^ ((c&1)<<3)]
    __shared__ __align__(16) _Float16 vbufT[16 * 524];   // 16.4 KB, [d][c], stride 524

    const int rt = blockIdx.x, h = blockIdx.y, b = blockIdx.z;
    const int tid = threadIdx.x, wid = tid >> 6, lane = tid & 63;
    const int quad = lane >> 4, fr = lane & 15;
    const int row_m = rt * 64 + wid * 16 + fr;

    // ---- this lane's q fragment: B[k=quad*4+j][n=fr] = q[row fr][d=quad*4+j] ----
    const f16x4 qf = *(const f16x4*)(q + (size_t)(b * R_ + row_m) * 256 + h * 16 + (quad << 2));

    // ---- stage K [c][d] (xor-swizzled) and V^T [d][c] for all 512 cols ----
    {
        const int lc0 = tid >> 1, dp = (tid & 1) * 8;
        const size_t gbase = (size_t)(b * C_) * 256 + h * 16 + dp;
#pragma unroll
        for (int it = 0; it < 4; it++) {
            const int lc = it * 128 + lc0;
            const size_t g = gbase + (size_t)lc * 256;
            *(short8*)(&kbuf[lc * 16 + (dp ^ ((lc & 1) << 3))]) = *(const short8*)(k + g);
            const short8 vv = *(const short8*)(v + g);
#pragma unroll
            for (int u = 0; u < 8; u++) vbufT[(dp + u) * 524 + lc] = ((const _Float16*)&vv)[u];
        }
    }

    // ---- per-head MLP weights (packed f16 pairs over hidden dim m) ----
    h2 w1a2[8], w1b2[8], b1h[8], w2p[8];
#pragma unroll
    for (int i = 0; i < 8; i++) {
        h2 t;
        t.x = (f16)m1w[h * 32 + 2 * i];      t.y = (f16)m1w[h * 32 + 2 * i + 1];      w1a2[i] = t;
        t.x = (f16)m1w[h * 32 + 16 + 2 * i]; t.y = (f16)m1w[h * 32 + 17 + 2 * i];     w1b2[i] = t;
        t.x = (f16)m1b[h * 16 + 2 * i];      t.y = (f16)m1b[h * 16 + 2 * i + 1];      b1h[i] = t;
        t.x = (f16)m2w[h * 16 + 2 * i];      t.y = (f16)m2w[h * 16 + 2 * i + 1];      w2p[i] = t;
    }
    const float b2v = m2b[h];
    const h2 zero2 = (h2)(f16)0;

    // ---- cost prefetch (chunk 0) ----
    const float* crow = cost + (size_t)(b * R_ + row_m) * C_;
    float4 cf[2][8];
#pragma unroll
    for (int t = 0; t < 8; t++) cf[0][t] = *(const float4*)(crow + t * 16 + (quad << 2));

    __syncthreads();

    f32x4 oaccT = (f32x4){0.f, 0.f, 0.f, 0.f};
    float lsum = 0.f, m_run = -3.0e30f;

#pragma unroll
    for (int cs = 0; cs < 4; cs++) {
        // prefetch next chunk's cost (covered by this chunk's compute)
        if (cs < 3) {
#pragma unroll
            for (int t = 0; t < 8; t++)
                cf[(cs + 1) & 1][t] = *(const float4*)(crow + (cs + 1) * 128 + t * 16 + (quad << 2));
        }
        // ---- S^T via MFMA: sc[t][i] = dot(q[fr], k[c]) at c = cs*128 + t*16 + quad*4 + i ----
        f32x4 sc[8];
#pragma unroll
        for (int t = 0; t < 8; t++) {
            const int c = cs * 128 + t * 16 + fr;
            const f16x4 kf = *(const f16x4*)(&kbuf[c * 16 + ((quad << 2) ^ ((fr & 1) << 3))]);
            sc[t] = __builtin_amdgcn_mfma_f32_16x16x16f16(kf, qf, (f32x4){0.f, 0.f, 0.f, 0.f}, 0, 0, 0);
        }
        // ---- per-score 2->16->1 mixing MLP (h2 over hidden dim) ----
#pragma unroll
        for (int t = 0; t < 8; t++) {
            const float4 cq = cf[cs & 1][t];
            const float carr[4] = {cq.x, cq.y, cq.z, cq.w};
#pragma unroll
            for (int i = 0; i < 4; i++) {
                const f16 doth = (f16)sc[t][i], csth = (f16)carr[i];
                h2 dot2; dot2.x = doth; dot2.y = doth;
                h2 cst2; cst2.x = csth; cst2.y = csth;
                h2 acc2 = zero2;
#pragma unroll
                for (int mm = 0; mm < 8; mm++) {
                    h2 tt = dot2 * w1a2[mm] + b1h[mm];
                    tt = cst2 * w1b2[mm] + tt;
                    tt = __builtin_elementwise_max(tt, zero2);
                    acc2 = tt * w2p[mm] + acc2;
                }
                sc[t][i] = b2v + (float)acc2.x + (float)acc2.y;
            }
        }
        // ---- online softmax update (row = fr; lane-local + 2 shuffles) ----
        float mx = fmaxf(fmaxf(sc[0][0], sc[0][1]), fmaxf(sc[0][2], sc[0][3]));
#pragma unroll
        for (int t = 1; t < 8; t++)
            mx = fmaxf(mx, fmaxf(fmaxf(sc[t][0], sc[t][1]), fmaxf(sc[t][2], sc[t][3])));
        mx = fmaxf(mx, __shfl_xor(mx, 16, 64));
        mx = fmaxf(mx, __shfl_xor(mx, 32, 64));
        const float mnew = fmaxf(m_run, mx);
        const float fac = __expf(m_run - mnew);
        m_run = mnew;
        lsum *= fac;
        oaccT[0] *= fac; oaccT[1] *= fac; oaccT[2] *= fac; oaccT[3] *= fac;

        // ---- exp + PV MFMA: B-frag = exp'd scores in-register (i == j) ----
#pragma unroll
        for (int p = 0; p < 8; p++) {
            f16x4 pf;
#pragma unroll
            for (int j = 0; j < 4; j++) {
                const float e = __expf(sc[p][j] - m_run);
                lsum += e;
                pf[j] = (f16)e;
            }
            const f16x4 vf = *(const f16x4*)(&vbufT[fr * 524 + cs * 128 + p * 16 + (quad << 2)]);
            oaccT = __builtin_amdgcn_mfma_f32_16x16x16f16(vf, pf, oaccT, 0, 0, 0);
        }
    }

    // ---- normalize and write: lane holds O[row fr][d = quad*4 + i] ----
    lsum += __shfl_xor(lsum, 16, 64);
    lsum += __shfl_xor(lsum, 32, 64);
    const float inv = 1.f / lsum;
    short4v o;
#pragma unroll
    for (int i = 0; i < 4; i++) o[i] = __builtin_bit_cast(short, __float2bfloat16(oaccT[i] * inv));
    *(short4v*)((short*)sa + (size_t)(b * R_ + row_m) * 256 + h * 16 + (quad << 2)) = o;
}

// ================= K7: final instance-norm from raw stats -> fp32 out =================
__global__ __launch_bounds__(256) void apply_in2_kernel(
    const bf16* __restrict__ xin, const float* __restrict__ stats,
    const float* __restrict__ g, const float* __restrict__ be, float* __restrict__ outp)
{
    const int base = (blockIdx.x * 256 + threadIdx.x) * 4;  // < 524288
    const int b = base >> 17;
    const bf162* xp = (const bf162*)(xin + base);
    const float2 x0 = __bfloat1622float2(xp[0]), x1 = __bfloat1622float2(xp[1]);
    const float xv[4] = {x0.x, x0.y, x1.x, x1.y};
    float4 rr;
    float* rp = (float*)&rr;
#pragma unroll
    for (int j = 0; j < 4; j++) {
        const int e = (base & 255) + j;
        const float s = stats[b * 256 + e], sq = stats[1024 + b * 256 + e];
        const float mn = s * (1.f / 512.f);
        float var = sq * (1.f / 512.f) - mn * mn; var = fmaxf(var, 0.f);
        rp[j] = (xv[j] - mn) * rsqrtf(var + 1e-5f) * g[e] + be[e];
    }
    *(float4*)(outp + base) = rr;
}

extern "C" void kernel_launch(void* const* d_in, const int* in_sizes, int n_in,
                              void* d_out, int out_size, void* d_ws, size_t ws_size,
                              hipStream_t stream)
{
    (void)in_sizes; (void)n_in; (void)out_size; (void)ws_size;
    const float* row_emb = (const float*)d_in[0];
    const float* col_emb = (const float*)d_in[1];
    const float* cost    = (const float*)d_in[2];
    const float* Wq  = (const float*)d_in[3];
    const float* Wk  = (const float*)d_in[4];
    const float* Wv  = (const float*)d_in[5];
    const float* m1w = (const float*)d_in[6];
    const float* m1b = (const float*)d_in[7];
    const float* m2w = (const float*)d_in[8];
    const float* m2b = (const float*)d_in[9];
    const float* Wc  = (const float*)d_in[10];
    const float* bc  = (const float*)d_in[11];
    const float* W1  = (const float*)d_in[12];
    const float* b1  = (const float*)d_in[13];
    const float* W2  = (const float*)d_in[14];
    const float* b2  = (const float*)d_in[15];
    const float* g1  = (const float*)d_in[16];
    const float* be1 = (const float*)d_in[17];
    const float* g2  = (const float*)d_in[18];
    const float* be2 = (const float*)d_in[19];
    float* out = (float*)d_out;

    // ---- workspace layout (~10 MB used) ----
    char* w = (char*)d_ws;
    const size_t MB = 1u << 20;
    f16*  sq  = (f16*)(w + 0 * MB);        // 1 MB [K12..K3]
    f16*  sk  = (f16*)(w + 1 * MB);        // 1 MB [K12..K3]
    f16*  sv  = (f16*)(w + 2 * MB);        // 1 MB [K12..K3]
    bf16* sa  = (bf16*)(w + 3 * MB);       // 1 MB [K3..K4]
    bf16* sy  = (bf16*)(w + 4 * MB);       // 1 MB [K4..K6]
    bf16* st  = (bf16*)(w + 5 * MB);       // 1 MB [K6..K7]
    bf16* shm = (bf16*)(w + 6 * MB);       // 2 MB [K5..K6]
    bf16* WcT = (bf16*)(w + 8 * MB);       // 128 KB
    bf16* W1T = WcT + 65536;               // 256 KB
    bf16* W2T = W1T + 131072;              // 256 KB
    float* stats1 = (float*)(w + 9 * MB);  // 8 KB
    float* stats2 = stats1 + 2048;         // 8 KB

    const dim3 blk(256);

    // K12: fused prep (Wc/W1/W2 transpose + stats zero) || QKV with inline W transpose
    prep_qkv_kernel<<<dim3(1104), blk, 0, stream>>>(
        row_emb, col_emb, Wq, Wk, Wv, Wc, W1, W2,
        WcT, W1T, W2T, stats1, sq, sk, sv);

    // K3: fully-fused attention (512 WGs, 33 KB LDS, MFMA QK^T + MFMA PV, online softmax)
    attn_kernel<<<dim3(8, 16, 4), blk, 0, stream>>>(
        sq, sk, sv, cost, m1w, m1b, m2w, m2b, sa);

    // K4: y = sa @ Wc + bc + row_emb -> sy (+stats1)  [512 WGs, 32x32]
    mfma_gemm_kernel<0, bf16, 32, 32, true, 1, false, true><<<dim3(8, 64), blk, 0, stream>>>(
        sa, WcT, bc, row_emb, nullptr, nullptr, nullptr, stats1, sy, 2048, 256, 256);

    // K5: hm = relu(norm1(sy) @ W1 + b1) -> shm  [512 WGs, 32x64, norm precomputed in LDS]
    mfma_gemm_kernel<2, bf16, 32, 64, true, 0, true, false><<<dim3(8, 64), blk, 0, stream>>>(
        sy, W1T, b1, nullptr, stats1, g1, be1, nullptr, shm, 2048, 512, 256);

    // K6: t = hm @ W2 + b2 + norm1(sy) -> st (+stats2)  [512 WGs, 32x32]
    mfma_gemm_kernel<0, bf16, 32, 32, true, 3, false, true><<<dim3(8, 64), blk, 0, stream>>>(
        shm, W2T, b2, sy, stats1, g1, be1, stats2, st, 2048, 256, 512);

    // K7: out = norm2(st)
    apply_in2_kernel<<<dim3(512), blk, 0, stream>>>(st, stats2, g2, be2, out);
}